// Round 4
// baseline (10955.994 us; speedup 1.0000x reference)
//
#include <hip/hip_runtime.h>
#include <math.h>

// Problem constants (fixed by the reference)
#define BQ 32
#define DQ 512
#define TQ 2048
#define VQ 1024
#define QQ 6
#define NQ (BQ * TQ)                 // 65536 rows
#define NDQ ((size_t)NQ * DQ)        // 33,554,432 elements

// ---------------------------------------------------------------------------
// B-tile LDS swizzle (layout only; values untouched)
__device__ __forceinline__ int bswz(int kk, int vv) {
    return vv ^ ((((kk & 7) ^ ((vv >> 5) & 7))) << 2);
}

// ---------------------------------------------------------------------------
// numpy-pairwise fp32 ||c||^2: per 512-row = (P0+P1)+(P2+P3), each P = 128-block
// with 8 accumulators + ((r0+r1)+(r2+r3))+((r4+r5)+(r6+r7)) tree. 32 lanes/code.
__global__ void cnorm32_kernel(const float* __restrict__ cb, float* __restrict__ cn) {
    #pragma clang fp contract(off)
    int gw   = (blockIdx.x * blockDim.x + threadIdx.x) >> 5;  // 32-lane group
    int l    = threadIdx.x & 31;
    if (gw >= QQ * VQ) return;
    const float* row = cb + (size_t)gw * DQ;
    const int c = l >> 3, j = l & 7;
    float acc = 0.f;
    #pragma unroll
    for (int m = 0; m < 16; m++) {
        float v = row[c * 128 + m * 8 + j];
        float a = v * v;          // separate fp32 round (numpy temp array)
        acc = acc + a;            // sequential ascending m
    }
    float s = acc + __shfl_xor(acc, 1, 64);   // (r0+r1) etc. (commutative)
    s = s + __shfl_xor(s, 2, 64);             // +(r2+r3) pair
    s = s + __shfl_xor(s, 4, 64);             // full 8-tree -> Pc
    float t = s + __shfl_xor(s, 8, 64);       // (P0+P1), (P2+P3)
    t = t + __shfl_xor(t, 16, 64);            // (P0+P1)+(P2+P3)
    if (l == 0) cn[gw] = t;
}

// ---------------------------------------------------------------------------
// One residual-VQ stage, fp32 numpy-replicated index pipeline.
__global__ __launch_bounds__(256) void vq32_pass(
    const float* __restrict__ x, const float* __restrict__ cb_all,
    const float* __restrict__ cn_all,
    float* __restrict__ out,       // d_out base; written only at q==Q-1
    float* __restrict__ idx_out,   // d_out + ND + 3, (B,T,Q) as float
    int* __restrict__ hist, double* __restrict__ loss_acc, int q)
{
    #pragma clang fp contract(off)
    __shared__ float As[32][64];
    __shared__ float Bs[32][256];
    __shared__ int   hq[64][QQ];
    __shared__ int   idx_l[64];
    __shared__ float PL[64][4];
    __shared__ float rn_l[64];
    __shared__ double redbuf[4];

    const int tid = threadIdx.x;
    const int n0  = blockIdx.x * 64;
    const int b   = n0 / TQ;
    const int t0  = n0 % TQ;
    const float* cb = cb_all + (size_t)q * VQ * DQ;
    const float* cn = cn_all + q * VQ;

    if (tid < 64)
        for (int j = 0; j < q; j++)
            hq[tid][j] = (int)idx_out[(size_t)(n0 + tid) * QQ + j];
    __syncthreads();

    const int rr  = tid & 63;
    const int kkb = tid >> 6;

    // fp32 residual replay (exact reference chain: qst = r+(c-r); r = r-qst)
    auto stageA = [&](int kt) {
        const int k0 = kt * 32 + kkb * 8;
        const float* xp = x + ((size_t)b * DQ + k0) * TQ + t0 + rr;
        float r[8];
        #pragma unroll
        for (int u = 0; u < 8; u++) r[u] = xp[(size_t)u * TQ];
        for (int j = 0; j < q; j++) {
            const float* cp = cb_all + ((size_t)j * VQ + hq[rr][j]) * DQ + k0;
            #pragma unroll
            for (int u = 0; u < 8; u++) {
                float cv = cp[u];
                float tt = cv - r[u];
                float qs = r[u] + tt;
                r[u] = r[u] - qs;
            }
        }
        #pragma unroll
        for (int u = 0; u < 8; u++) As[kkb * 8 + u][rr] = r[u];
    };

    // ---------- Phase 0: rn = numpy-pairwise fp32 sum of r*r ----------
    {
        float racc[8];
        #pragma unroll
        for (int j = 0; j < 8; j++) racc[j] = 0.f;
        for (int kt = 0; kt < 16; kt++) {
            __syncthreads();
            stageA(kt);
            __syncthreads();
            if (kkb == (kt >> 2)) {          // my 128-chunk c == kkb
                #pragma unroll
                for (int mm = 0; mm < 4; mm++)     // ascending m within chunk
                    #pragma unroll
                    for (int j = 0; j < 8; j++) {
                        float v = As[mm * 8 + j][rr];
                        float a = v * v;
                        racc[j] = racc[j] + a;
                    }
            }
        }
        float s01 = racc[0] + racc[1], s23 = racc[2] + racc[3];
        float s45 = racc[4] + racc[5], s67 = racc[6] + racc[7];
        PL[rr][kkb] = (s01 + s23) + (s45 + s67);
        __syncthreads();
        if (tid < 64) {
            float a01 = PL[tid][0] + PL[tid][1];
            float a23 = PL[tid][2] + PL[tid][3];
            rn_l[tid] = a01 + a23;
        }
        __syncthreads();
    }

    // ---------- Phase 1: fp32 FMA distance GEMM + argmin ----------
    const int ty = tid >> 5;   // 8 row groups x 8 rows
    const int tx = tid & 31;   // 32 code groups x 8 codes

    float best[8]; int bidx[8];
    #pragma unroll
    for (int i = 0; i < 8; i++) { best[i] = INFINITY; bidx[i] = 0; }

    for (int vt = 0; vt < 4; vt++) {
        const int v0 = vt * 256;
        float acc[8][8];
        #pragma unroll
        for (int i = 0; i < 8; i++)
            #pragma unroll
            for (int j = 0; j < 8; j++) acc[i][j] = 0.f;

        for (int kt = 0; kt < 16; kt++) {
            __syncthreads();
            stageA(kt);
            {
                int kk = tid & 31, vb = tid >> 5;
                const float* bp = cb + (size_t)(v0 + vb * 32) * DQ + kt * 32 + kk;
                #pragma unroll
                for (int w = 0; w < 32; w++)
                    Bs[kk][bswz(kk, vb * 32 + w)] = bp[(size_t)w * DQ];
            }
            __syncthreads();
            // strict ascending-k fp32 FMA chain per (row,code) — BLAS order
            for (int kk = 0; kk < 32; kk++) {
                const float4 a0 = *(const float4*)&As[kk][ty * 8];
                const float4 a1 = *(const float4*)&As[kk][ty * 8 + 4];
                const float4 b0 = *(const float4*)&Bs[kk][bswz(kk, tx * 8)];
                const float4 b1 = *(const float4*)&Bs[kk][bswz(kk, tx * 8 + 4)];
                const float av[8] = {a0.x,a0.y,a0.z,a0.w,a1.x,a1.y,a1.z,a1.w};
                const float bv[8] = {b0.x,b0.y,b0.z,b0.w,b1.x,b1.y,b1.z,b1.w};
                #pragma unroll
                for (int i = 0; i < 8; i++)
                    #pragma unroll
                    for (int j = 0; j < 8; j++)
                        acc[i][j] = fmaf(av[i], bv[j], acc[i][j]);
            }
        }
        // d = fl(fl(rn - 2M) + cn)  (numpy's (rn - M2) + cn, M2 = 2M bitwise)
        #pragma unroll
        for (int j = 0; j < 8; j++) {
            const int v = v0 + tx * 8 + j;
            const float cnv = cn[v];
            #pragma unroll
            for (int i = 0; i < 8; i++) {
                float m2 = 2.0f * acc[i][j];
                float t1 = rn_l[ty * 8 + i] - m2;
                float d  = t1 + cnv;
                if (d < best[i]) { best[i] = d; bidx[i] = v; }
            }
        }
    }

    // (min, argmin) butterfly with first-index tie rule
    #pragma unroll
    for (int i = 0; i < 8; i++) {
        float v = best[i]; int ix = bidx[i];
        #pragma unroll
        for (int m = 16; m >= 1; m >>= 1) {
            float ov = __shfl_xor(v, m, 64);
            int   oi = __shfl_xor(ix, m, 64);
            if (ov < v || (ov == v && oi < ix)) { v = ov; ix = oi; }
        }
        if (tx == 0) idx_l[ty * 8 + i] = ix;
    }
    __syncthreads();

    if (tid < 64) {
        int ix = idx_l[tid];
        idx_out[(size_t)(n0 + tid) * QQ + q] = (float)ix;
        atomicAdd(&hist[q * VQ + ix], 1);
    }
    __syncthreads();

    // ---------- Phase 2: loss (+ final output replay) ----------
    double lsum = 0.0;
    {
        const int kb = tid >> 6;
        int hh[QQ];
        for (int j = 0; j < q; j++) hh[j] = hq[rr][j];
        hh[q] = idx_l[rr];
        for (int w = 0; w < 128; w++) {
            const int k = kb * 128 + w;
            const size_t o = ((size_t)b * DQ + k) * TQ + t0 + rr;
            float r  = x[o];
            float qa = 0.f;
            float e  = 0.f;
            for (int j = 0; j <= q; j++) {
                float cv = cb_all[((size_t)j * VQ + hh[j]) * DQ + k];
                if (j == q) e = r - cv;        // res_old - quant (this stage)
                float tt = cv - r;
                float qs = r + tt;             // quant_st, fp32 reference chain
                qa = qa + qs;                  // quantized_out accumulation
                r  = r - qs;                   // residual update
            }
            lsum += (double)e * (double)e;
            if (q == QQ - 1) out[o] = qa;
        }
    }
    #pragma unroll
    for (int m = 32; m >= 1; m >>= 1) lsum += __shfl_xor(lsum, m, 64);
    if ((tid & 63) == 0) redbuf[tid >> 6] = lsum;
    __syncthreads();
    if (tid == 0)
        atomicAdd(loss_acc + q, redbuf[0] + redbuf[1] + redbuf[2] + redbuf[3]);
}

// ---------------------------------------------------------------------------
// Scalars: usage%, loss, perplexity averaged over Q.
__global__ void finalize_kernel(const int* __restrict__ hist,
                                const double* __restrict__ loss_acc,
                                float* __restrict__ outs) {
    int lane = threadIdx.x;  // blockDim = 64
    float usage_sum = 0.f, perp_sum = 0.f;
    for (int q = 0; q < QQ; q++) {
        int nz = 0; float ent = 0.f;
        for (int v = lane; v < VQ; v += 64) {
            int c = hist[q * VQ + v];
            if (c > 0) {
                nz++;
                float p = (float)c / (float)NQ;
                ent += p * logf(p);
            }
        }
        #pragma unroll
        for (int m = 32; m >= 1; m >>= 1) {
            nz  += __shfl_xor(nz, m, 64);
            ent += __shfl_xor(ent, m, 64);
        }
        usage_sum += (float)nz / (float)VQ * 100.f;
        perp_sum  += expf(-ent);
    }
    if (lane == 0) {
        outs[0] = usage_sum / QQ;
        double ls = 0.0;
        for (int q = 0; q < QQ; q++)
            ls += loss_acc[q] * 1.25 / (double)NDQ;
        outs[1] = (float)(ls / QQ);
        outs[2] = perp_sum / QQ;
    }
}

// ---------------------------------------------------------------------------
extern "C" void kernel_launch(void* const* d_in, const int* in_sizes, int n_in,
                              void* d_out, int out_size, void* d_ws, size_t ws_size,
                              hipStream_t stream) {
    const float* x  = (const float*)d_in[0];
    const float* cb = (const float*)d_in[1];

    float* outp    = (float*)d_out;          // [0, ND): quantized_out
    float* scal    = outp + NDQ;             // usage, loss, perp
    float* idx_out = scal + 3;               // (B,T,Q) indices as float

    int*    hist     = (int*)d_ws;                                     // Q*V ints
    double* loss_acc = (double*)((char*)d_ws + QQ * VQ * sizeof(int)); // Q doubles
    float*  cn32     = (float*)(loss_acc + QQ);                        // Q*V floats

    hipMemsetAsync(d_ws, 0, QQ * VQ * sizeof(int) + QQ * sizeof(double), stream);

    cnorm32_kernel<<<(QQ * VQ) / 8, 256, 0, stream>>>(cb, cn32);

    for (int q = 0; q < QQ; q++) {
        vq32_pass<<<NQ / 64, 256, 0, stream>>>(x, cb, cn32, outp, idx_out,
                                               hist, loss_acc, q);
    }

    finalize_kernel<<<1, 64, 0, stream>>>(hist, loss_acc, scal);
}

// Round 5
// 9329.441 us; speedup vs baseline: 1.1743x; 1.1743x over previous
//
#include <hip/hip_runtime.h>
#include <math.h>

// Problem constants (fixed by the reference)
#define BQ 32
#define DQ 512
#define TQ 2048
#define VQ 1024
#define QQ 6
#define NQ (BQ * TQ)                 // 65536 rows
#define NDQ ((size_t)NQ * DQ)        // 33,554,432 elements

// ---------------------------------------------------------------------------
// B-tile LDS swizzle (layout only; values untouched)
__device__ __forceinline__ int bswz(int kk, int vv) {
    return vv ^ ((((kk & 7) ^ ((vv >> 5) & 7))) << 2);
}

// ---------------------------------------------------------------------------
// numpy-pairwise fp32 ||c||^2: per 512-row = (P0+P1)+(P2+P3), each P = 128-block
// with 8 accumulators + ((r0+r1)+(r2+r3))+((r4+r5)+(r6+r7)) tree. 32 lanes/code.
__global__ void cnorm32_kernel(const float* __restrict__ cb, float* __restrict__ cn) {
    #pragma clang fp contract(off)
    int gw   = (blockIdx.x * blockDim.x + threadIdx.x) >> 5;  // 32-lane group
    int l    = threadIdx.x & 31;
    if (gw >= QQ * VQ) return;
    const float* row = cb + (size_t)gw * DQ;
    const int c = l >> 3, j = l & 7;
    float acc = 0.f;
    #pragma unroll
    for (int m = 0; m < 16; m++) {
        float v = row[c * 128 + m * 8 + j];
        float a = v * v;          // separate fp32 round (numpy temp array)
        acc = acc + a;            // sequential ascending m
    }
    float s = acc + __shfl_xor(acc, 1, 64);   // (r0+r1) etc.
    s = s + __shfl_xor(s, 2, 64);             // +(r2+r3) pair
    s = s + __shfl_xor(s, 4, 64);             // full 8-tree -> Pc
    float t = s + __shfl_xor(s, 8, 64);       // (P0+P1), (P2+P3)
    t = t + __shfl_xor(t, 16, 64);            // (P0+P1)+(P2+P3)
    if (l == 0) cn[gw] = t;
}

// ---------------------------------------------------------------------------
// One residual-VQ stage, fp32 numpy-replicated index pipeline.
// Residual lives in res (= d_out region, (B,D,T) layout); stage q reads the
// residual stage q-1 stored (bitwise identical to the reference replay chain)
// and writes the updated residual (or the final quantized output at q==Q-1).
__global__ __launch_bounds__(256) void vq32_pass(
    const float* __restrict__ x, const float* __restrict__ cb_all,
    const float* __restrict__ cn_all,
    float* __restrict__ res,       // d_out base; residual chain, final: quantized
    float* __restrict__ idx_out,   // d_out + ND + 3, (B,T,Q) as float
    int* __restrict__ hist, double* __restrict__ loss_acc, int q)
{
    #pragma clang fp contract(off)
    __shared__ float As[32][64];     // [kk][row]   8 KiB
    __shared__ float Bs[32][256];    // [kk][code]  32 KiB; reused as c2[64][128]
    __shared__ int   idx_l[64];
    __shared__ float PL[64][4];
    __shared__ float rn_l[64];
    __shared__ double redbuf[4];

    const int tid = threadIdx.x;
    const int n0  = blockIdx.x * 64;
    const int b   = n0 / TQ;
    const int t0  = n0 % TQ;
    const float* cb  = cb_all + (size_t)q * VQ * DQ;
    const float* cn  = cn_all + q * VQ;
    const float* src = (q == 0) ? x : res;

    const int rr  = tid & 63;
    const int kkb = tid >> 6;

    // ---------- Phase 0: rn = numpy-pairwise fp32 sum of r*r ----------
    {
        float racc[8];
        #pragma unroll
        for (int j = 0; j < 8; j++) racc[j] = 0.f;
        for (int kt = 0; kt < 16; kt++) {
            __syncthreads();
            {   // stage A: coalesced direct load of residual
                const float* sp = src + ((size_t)b * DQ + kt * 32) * TQ + t0 + rr;
                #pragma unroll
                for (int u = 0; u < 8; u++)
                    As[kkb * 8 + u][rr] = sp[(size_t)(kkb * 8 + u) * TQ];
            }
            __syncthreads();
            if (kkb == (kt >> 2)) {          // my 128-chunk c == kkb
                #pragma unroll
                for (int mm = 0; mm < 4; mm++)     // ascending m within chunk
                    #pragma unroll
                    for (int j = 0; j < 8; j++) {
                        float v = As[mm * 8 + j][rr];
                        float a = v * v;
                        racc[j] = racc[j] + a;
                    }
            }
        }
        float s01 = racc[0] + racc[1], s23 = racc[2] + racc[3];
        float s45 = racc[4] + racc[5], s67 = racc[6] + racc[7];
        PL[rr][kkb] = (s01 + s23) + (s45 + s67);
        __syncthreads();
        if (tid < 64) {
            float a01 = PL[tid][0] + PL[tid][1];
            float a23 = PL[tid][2] + PL[tid][3];
            rn_l[tid] = a01 + a23;
        }
        __syncthreads();
    }

    // ---------- Phase 1: fp32 FMA distance GEMM + argmin ----------
    const int ty = tid >> 5;   // 8 row groups x 8 rows
    const int tx = tid & 31;   // 32 code groups x 8 codes

    float best[8]; int bidx[8];
    #pragma unroll
    for (int i = 0; i < 8; i++) { best[i] = INFINITY; bidx[i] = 0; }

    for (int vt = 0; vt < 4; vt++) {
        const int v0 = vt * 256;
        float acc[8][8];
        #pragma unroll
        for (int i = 0; i < 8; i++)
            #pragma unroll
            for (int j = 0; j < 8; j++) acc[i][j] = 0.f;

        for (int kt = 0; kt < 16; kt++) {
            __syncthreads();
            {   // stage A: coalesced direct load of residual
                const float* sp = src + ((size_t)b * DQ + kt * 32) * TQ + t0 + rr;
                #pragma unroll
                for (int u = 0; u < 8; u++)
                    As[kkb * 8 + u][rr] = sp[(size_t)(kkb * 8 + u) * TQ];
            }
            {   // stage B: 256 codes x 32 k (coalesced over k), swizzled
                int kk = tid & 31, vb = tid >> 5;
                const float* bp = cb + (size_t)(v0 + vb * 32) * DQ + kt * 32 + kk;
                #pragma unroll
                for (int w = 0; w < 32; w++)
                    Bs[kk][bswz(kk, vb * 32 + w)] = bp[(size_t)w * DQ];
            }
            __syncthreads();
            // strict ascending-k fp32 FMA chain per (row,code) — BLAS order
            for (int kk = 0; kk < 32; kk++) {
                const float4 a0 = *(const float4*)&As[kk][ty * 8];
                const float4 a1 = *(const float4*)&As[kk][ty * 8 + 4];
                const float4 b0 = *(const float4*)&Bs[kk][bswz(kk, tx * 8)];
                const float4 b1 = *(const float4*)&Bs[kk][bswz(kk, tx * 8 + 4)];
                const float av[8] = {a0.x,a0.y,a0.z,a0.w,a1.x,a1.y,a1.z,a1.w};
                const float bv[8] = {b0.x,b0.y,b0.z,b0.w,b1.x,b1.y,b1.z,b1.w};
                #pragma unroll
                for (int i = 0; i < 8; i++)
                    #pragma unroll
                    for (int j = 0; j < 8; j++)
                        acc[i][j] = fmaf(av[i], bv[j], acc[i][j]);
            }
        }
        // d = fl(fl(rn - 2M) + cn)
        #pragma unroll
        for (int j = 0; j < 8; j++) {
            const int v = v0 + tx * 8 + j;
            const float cnv = cn[v];
            #pragma unroll
            for (int i = 0; i < 8; i++) {
                float m2 = 2.0f * acc[i][j];
                float t1 = rn_l[ty * 8 + i] - m2;
                float d  = t1 + cnv;
                if (d < best[i]) { best[i] = d; bidx[i] = v; }
            }
        }
    }

    // (min, argmin) butterfly with first-index tie rule
    #pragma unroll
    for (int i = 0; i < 8; i++) {
        float v = best[i]; int ix = bidx[i];
        #pragma unroll
        for (int m = 16; m >= 1; m >>= 1) {
            float ov = __shfl_xor(v, m, 64);
            int   oi = __shfl_xor(ix, m, 64);
            if (ov < v || (ov == v && oi < ix)) { v = ov; ix = oi; }
        }
        if (tx == 0) idx_l[ty * 8 + i] = ix;
    }
    __syncthreads();

    if (tid < 64) {
        int ix = idx_l[tid];
        idx_out[(size_t)(n0 + tid) * QQ + q] = (float)ix;
        atomicAdd(&hist[q * VQ + ix], 1);
    }

    // ---------- Phase 2: residual update + loss (+ final output) ----------
    float* c2 = &Bs[0][0];   // reuse as [64 rows][128 k] with XOR swizzle
    double lsum = 0.0;
    for (int kc = 0; kc < 4; kc++) {
        __syncthreads();
        {   // stage the selected code rows (coalesced 512B per row)
            int kk = tid & 127, r2 = tid >> 7;
            #pragma unroll
            for (int p = 0; p < 32; p++) {
                int rw = p * 2 + r2;
                const float* crow = cb + (size_t)idx_l[rw] * DQ + kc * 128;
                c2[rw * 128 + (kk ^ (rw & 31))] = crow[kk];
            }
        }
        __syncthreads();
        {
            int kb = tid >> 6;
            #pragma unroll
            for (int w = 0; w < 32; w++) {
                int kk = kb * 32 + w;
                int k  = kc * 128 + kk;
                size_t o = ((size_t)b * DQ + k) * TQ + t0 + rr;
                float cv = c2[rr * 128 + (kk ^ (rr & 31))];
                float r_old = src[o];          // x at q==0, else stored residual
                float e  = r_old - cv;         // loss term (exact ref chain)
                lsum += (double)e * (double)e;
                float tt = cv - r_old;
                float qs = r_old + tt;         // quant_st, fp32 reference chain
                float rn2 = r_old - qs;        // updated residual
                if (q < QQ - 1) res[o] = rn2;
                else            res[o] = x[o] - rn2;   // quantized_out = x - r_final
            }
        }
    }
    #pragma unroll
    for (int m = 32; m >= 1; m >>= 1) lsum += __shfl_xor(lsum, m, 64);
    if ((tid & 63) == 0) redbuf[tid >> 6] = lsum;
    __syncthreads();
    if (tid == 0)
        atomicAdd(loss_acc + q, redbuf[0] + redbuf[1] + redbuf[2] + redbuf[3]);
}

// ---------------------------------------------------------------------------
// Scalars: usage%, loss, perplexity averaged over Q.
__global__ void finalize_kernel(const int* __restrict__ hist,
                                const double* __restrict__ loss_acc,
                                float* __restrict__ outs) {
    int lane = threadIdx.x;  // blockDim = 64
    float usage_sum = 0.f, perp_sum = 0.f;
    for (int q = 0; q < QQ; q++) {
        int nz = 0; float ent = 0.f;
        for (int v = lane; v < VQ; v += 64) {
            int c = hist[q * VQ + v];
            if (c > 0) {
                nz++;
                float p = (float)c / (float)NQ;
                ent += p * logf(p);
            }
        }
        #pragma unroll
        for (int m = 32; m >= 1; m >>= 1) {
            nz  += __shfl_xor(nz, m, 64);
            ent += __shfl_xor(ent, m, 64);
        }
        usage_sum += (float)nz / (float)VQ * 100.f;
        perp_sum  += expf(-ent);
    }
    if (lane == 0) {
        outs[0] = usage_sum / QQ;
        double ls = 0.0;
        for (int q = 0; q < QQ; q++)
            ls += loss_acc[q] * 1.25 / (double)NDQ;
        outs[1] = (float)(ls / QQ);
        outs[2] = perp_sum / QQ;
    }
}

// ---------------------------------------------------------------------------
extern "C" void kernel_launch(void* const* d_in, const int* in_sizes, int n_in,
                              void* d_out, int out_size, void* d_ws, size_t ws_size,
                              hipStream_t stream) {
    const float* x  = (const float*)d_in[0];
    const float* cb = (const float*)d_in[1];

    float* res     = (float*)d_out;          // [0, ND): residual -> quantized_out
    float* scal    = res + NDQ;              // usage, loss, perp
    float* idx_out = scal + 3;               // (B,T,Q) indices as float

    int*    hist     = (int*)d_ws;                                     // Q*V ints
    double* loss_acc = (double*)((char*)d_ws + QQ * VQ * sizeof(int)); // Q doubles
    float*  cn32     = (float*)(loss_acc + QQ);                        // Q*V floats

    hipMemsetAsync(d_ws, 0, QQ * VQ * sizeof(int) + QQ * sizeof(double), stream);

    cnorm32_kernel<<<(QQ * VQ) / 8, 256, 0, stream>>>(cb, cn32);

    for (int q = 0; q < QQ; q++) {
        vq32_pass<<<NQ / 64, 256, 0, stream>>>(x, cb, cn32, res, idx_out,
                                               hist, loss_acc, q);
    }

    finalize_kernel<<<1, 64, 0, stream>>>(hist, loss_acc, scal);
}

// Round 6
// 6203.961 us; speedup vs baseline: 1.7660x; 1.5038x over previous
//
#include <hip/hip_runtime.h>
#include <math.h>

// Problem constants (fixed by the reference)
#define BQ 32
#define DQ 512
#define TQ 2048
#define VQ 1024
#define QQ 6
#define NQ (BQ * TQ)                 // 65536 rows
#define NDQ ((size_t)NQ * DQ)        // 33,554,432 elements

// ---------------------------------------------------------------------------
// B-tile LDS swizzle (layout only; values untouched)
__device__ __forceinline__ int bswz(int kk, int vv) {
    return vv ^ ((((kk & 7) ^ ((vv >> 5) & 7))) << 2);
}

// ---------------------------------------------------------------------------
// numpy-pairwise fp32 ||c||^2: per 512-row = (P0+P1)+(P2+P3), each P = 128-block
// with 8 accumulators + ((r0+r1)+(r2+r3))+((r4+r5)+(r6+r7)) tree. 32 lanes/code.
__global__ void cnorm32_kernel(const float* __restrict__ cb, float* __restrict__ cn) {
    #pragma clang fp contract(off)
    int gw   = (blockIdx.x * blockDim.x + threadIdx.x) >> 5;  // 32-lane group
    int l    = threadIdx.x & 31;
    if (gw >= QQ * VQ) return;
    const float* row = cb + (size_t)gw * DQ;
    const int c = l >> 3, j = l & 7;
    float acc = 0.f;
    #pragma unroll
    for (int m = 0; m < 16; m++) {
        float v = row[c * 128 + m * 8 + j];
        float a = v * v;          // separate fp32 round (numpy temp array)
        acc = acc + a;            // sequential ascending m
    }
    float s = acc + __shfl_xor(acc, 1, 64);   // (r0+r1) etc.
    s = s + __shfl_xor(s, 2, 64);             // +(r2+r3) pair
    s = s + __shfl_xor(s, 4, 64);             // full 8-tree -> Pc
    float t = s + __shfl_xor(s, 8, 64);       // (P0+P1), (P2+P3)
    t = t + __shfl_xor(t, 16, 64);            // (P0+P1)+(P2+P3)
    if (l == 0) cn[gw] = t;
}

// ---------------------------------------------------------------------------
// One residual-VQ stage, fp32 numpy-replicated index pipeline.
// Double-buffered LDS pipeline: issue loads early, compute, ds_write late.
__global__ __launch_bounds__(256) void vq32_pass(
    const float* __restrict__ x, const float* __restrict__ cb_all,
    const float* __restrict__ cn_all,
    float* __restrict__ res,       // d_out base; residual chain, final: quantized
    float* __restrict__ idx_out,   // d_out + ND + 3, (B,T,Q) as float
    int* __restrict__ hist, double* __restrict__ loss_acc, int q)
{
    #pragma clang fp contract(off)
    __shared__ float As[2][32][64];     // 16 KiB
    __shared__ float Bs[2][32][128];    // 32 KiB; phase-2 reuse as c2[64][128]
    __shared__ int   idx_l[64];
    __shared__ float PL[64][4];
    __shared__ float rn_l[64];
    __shared__ double redbuf[4];

    const int tid = threadIdx.x;
    const int n0  = blockIdx.x * 64;
    const int b   = n0 / TQ;
    const int t0  = n0 % TQ;
    const float* cb  = cb_all + (size_t)q * VQ * DQ;
    const float* cn  = cn_all + q * VQ;
    const float* src = (q == 0) ? x : res;

    const int rr  = tid & 63;
    const int kkb = tid >> 6;           // A-staging k-subgroup (8 k's)
    const int kks = tid & 31;           // B-staging k
    const int vbs = tid >> 5;           // B-staging code subgroup (16 codes)
    const int ty  = tid >> 5;           // compute: 8 row groups x 8 rows
    const int tx  = tid & 31;           // compute: 32 code groups x 4 codes

    float aR[8], bR[16];

    auto loadA = [&](int kt) {
        const float* sp = src + ((size_t)b * DQ + kt * 32) * TQ + t0 + rr;
        #pragma unroll
        for (int u = 0; u < 8; u++) aR[u] = sp[(size_t)(kkb * 8 + u) * TQ];
    };
    auto loadB = [&](int vt, int kt) {
        const float* bp = cb + (size_t)(vt * 128 + vbs * 16) * DQ + kt * 32 + kks;
        #pragma unroll
        for (int w = 0; w < 16; w++) bR[w] = bp[(size_t)w * DQ];
    };
    auto writeA = [&](int bf) {
        #pragma unroll
        for (int u = 0; u < 8; u++) As[bf][kkb * 8 + u][rr] = aR[u];
    };
    auto writeB = [&](int bf) {
        #pragma unroll
        for (int w = 0; w < 16; w++) Bs[bf][kks][bswz(kks, vbs * 16 + w)] = bR[w];
    };

    float racc[8];
    #pragma unroll
    for (int j = 0; j < 8; j++) racc[j] = 0.f;

    float best[8]; int bidx[8];
    #pragma unroll
    for (int i = 0; i < 8; i++) { best[i] = INFINITY; bidx[i] = 0; }

    // pipeline prologue: stage (vt=0, kt=0) into buffer 0
    loadA(0); loadB(0, 0);
    writeA(0); writeB(0);

    for (int vt = 0; vt < 8; vt++) {
        float acc[8][4];
        #pragma unroll
        for (int i = 0; i < 8; i++)
            #pragma unroll
            for (int j = 0; j < 4; j++) acc[i][j] = 0.f;

        int cur = 0;
        for (int kt = 0; kt < 16; kt++) {
            if (kt < 15) { loadA(kt + 1); loadB(vt, kt + 1); }   // issue early
            __syncthreads();                                     // buf[cur] ready
            // strict ascending-k fp32 FMA chain per (row,code) — BLAS order
            for (int kk = 0; kk < 32; kk++) {
                const float4 a0 = *(const float4*)&As[cur][kk][ty * 8];
                const float4 a1 = *(const float4*)&As[cur][kk][ty * 8 + 4];
                const float4 b0 = *(const float4*)&Bs[cur][kk][bswz(kk, tx * 4)];
                const float av[8] = {a0.x,a0.y,a0.z,a0.w,a1.x,a1.y,a1.z,a1.w};
                const float bv[4] = {b0.x,b0.y,b0.z,b0.w};
                #pragma unroll
                for (int i = 0; i < 8; i++)
                    #pragma unroll
                    for (int j = 0; j < 4; j++)
                        acc[i][j] = fmaf(av[i], bv[j], acc[i][j]);
            }
            // merged phase-0: rn partial sums in exact numpy order (vt==0)
            if (vt == 0 && (kt >> 2) == kkb) {
                #pragma unroll
                for (int mm = 0; mm < 4; mm++)
                    #pragma unroll
                    for (int j2 = 0; j2 < 8; j2++) {
                        float v = As[cur][mm * 8 + j2][rr];
                        float a2 = v * v;
                        racc[j2] = racc[j2] + a2;
                    }
            }
            if (kt < 15) { writeA(cur ^ 1); writeB(cur ^ 1); }   // write late
            cur ^= 1;
        }

        if (vt == 0) {
            float s01 = racc[0] + racc[1], s23 = racc[2] + racc[3];
            float s45 = racc[4] + racc[5], s67 = racc[6] + racc[7];
            PL[rr][kkb] = (s01 + s23) + (s45 + s67);
            __syncthreads();
            if (tid < 64) {
                float a01 = PL[tid][0] + PL[tid][1];
                float a23 = PL[tid][2] + PL[tid][3];
                rn_l[tid] = a01 + a23;
            }
            __syncthreads();
        }

        // prefetch next vt's first tile (hidden under fold)
        if (vt < 7) { loadA(0); loadB(vt + 1, 0); }

        // fold: d = fl(fl(rn - 2M) + cn), first-min over ascending v
        #pragma unroll
        for (int j = 0; j < 4; j++) {
            const int v = vt * 128 + tx * 4 + j;
            const float cnv = cn[v];
            #pragma unroll
            for (int i = 0; i < 8; i++) {
                float m2 = 2.0f * acc[i][j];
                float t1 = rn_l[ty * 8 + i] - m2;
                float d  = t1 + cnv;
                if (d < best[i]) { best[i] = d; bidx[i] = v; }
            }
        }

        if (vt < 7) { writeA(0); writeB(0); }   // safe: buf0 idle since kt=14
    }

    // (min, argmin) butterfly with first-index tie rule
    #pragma unroll
    for (int i = 0; i < 8; i++) {
        float v = best[i]; int ix = bidx[i];
        #pragma unroll
        for (int m = 16; m >= 1; m >>= 1) {
            float ov = __shfl_xor(v, m, 64);
            int   oi = __shfl_xor(ix, m, 64);
            if (ov < v || (ov == v && oi < ix)) { v = ov; ix = oi; }
        }
        if (tx == 0) idx_l[ty * 8 + i] = ix;
    }
    __syncthreads();

    if (tid < 64) {
        int ix = idx_l[tid];
        idx_out[(size_t)(n0 + tid) * QQ + q] = (float)ix;
        atomicAdd(&hist[q * VQ + ix], 1);
    }

    // ---------- Phase 2: residual update + loss (+ final output) ----------
    float* c2 = &Bs[0][0][0];   // reuse as [64 rows][128 k] with XOR swizzle
    double lsum = 0.0;
    for (int kc = 0; kc < 4; kc++) {
        __syncthreads();
        {   // stage the selected code rows (coalesced 512B per row)
            int kk = tid & 127, r2 = tid >> 7;
            #pragma unroll
            for (int p = 0; p < 32; p++) {
                int rw = p * 2 + r2;
                const float* crow = cb + (size_t)idx_l[rw] * DQ + kc * 128;
                c2[rw * 128 + (kk ^ (rw & 31))] = crow[kk];
            }
        }
        __syncthreads();
        {
            int kb = tid >> 6;
            #pragma unroll
            for (int w = 0; w < 32; w++) {
                int kk = kb * 32 + w;
                int k  = kc * 128 + kk;
                size_t o = ((size_t)b * DQ + k) * TQ + t0 + rr;
                float cv = c2[rr * 128 + (kk ^ (rr & 31))];
                float r_old = src[o];          // x at q==0, else stored residual
                float e  = r_old - cv;         // loss term (exact ref chain)
                lsum += (double)e * (double)e;
                float tt = cv - r_old;
                float qs = r_old + tt;         // quant_st, fp32 reference chain
                float rn2 = r_old - qs;        // updated residual
                if (q < QQ - 1) res[o] = rn2;
                else            res[o] = x[o] - rn2;   // quantized_out = x - r_final
            }
        }
    }
    #pragma unroll
    for (int m = 32; m >= 1; m >>= 1) lsum += __shfl_xor(lsum, m, 64);
    if ((tid & 63) == 0) redbuf[tid >> 6] = lsum;
    __syncthreads();
    if (tid == 0)
        atomicAdd(loss_acc + q, redbuf[0] + redbuf[1] + redbuf[2] + redbuf[3]);
}

// ---------------------------------------------------------------------------
// Scalars: usage%, loss, perplexity averaged over Q.
__global__ void finalize_kernel(const int* __restrict__ hist,
                                const double* __restrict__ loss_acc,
                                float* __restrict__ outs) {
    int lane = threadIdx.x;  // blockDim = 64
    float usage_sum = 0.f, perp_sum = 0.f;
    for (int q = 0; q < QQ; q++) {
        int nz = 0; float ent = 0.f;
        for (int v = lane; v < VQ; v += 64) {
            int c = hist[q * VQ + v];
            if (c > 0) {
                nz++;
                float p = (float)c / (float)NQ;
                ent += p * logf(p);
            }
        }
        #pragma unroll
        for (int m = 32; m >= 1; m >>= 1) {
            nz  += __shfl_xor(nz, m, 64);
            ent += __shfl_xor(ent, m, 64);
        }
        usage_sum += (float)nz / (float)VQ * 100.f;
        perp_sum  += expf(-ent);
    }
    if (lane == 0) {
        outs[0] = usage_sum / QQ;
        double ls = 0.0;
        for (int q = 0; q < QQ; q++)
            ls += loss_acc[q] * 1.25 / (double)NDQ;
        outs[1] = (float)(ls / QQ);
        outs[2] = perp_sum / QQ;
    }
}

// ---------------------------------------------------------------------------
extern "C" void kernel_launch(void* const* d_in, const int* in_sizes, int n_in,
                              void* d_out, int out_size, void* d_ws, size_t ws_size,
                              hipStream_t stream) {
    const float* x  = (const float*)d_in[0];
    const float* cb = (const float*)d_in[1];

    float* res     = (float*)d_out;          // [0, ND): residual -> quantized_out
    float* scal    = res + NDQ;              // usage, loss, perp
    float* idx_out = scal + 3;               // (B,T,Q) indices as float

    int*    hist     = (int*)d_ws;                                     // Q*V ints
    double* loss_acc = (double*)((char*)d_ws + QQ * VQ * sizeof(int)); // Q doubles
    float*  cn32     = (float*)(loss_acc + QQ);                        // Q*V floats

    hipMemsetAsync(d_ws, 0, QQ * VQ * sizeof(int) + QQ * sizeof(double), stream);

    cnorm32_kernel<<<(QQ * VQ) / 8, 256, 0, stream>>>(cb, cn32);

    for (int q = 0; q < QQ; q++) {
        vq32_pass<<<NQ / 64, 256, 0, stream>>>(x, cb, cn32, res, idx_out,
                                               hist, loss_acc, q);
    }

    finalize_kernel<<<1, 64, 0, stream>>>(hist, loss_acc, scal);
}